// Round 1
// baseline (232.327 us; speedup 1.0000x reference)
//
#include <hip/hip_runtime.h>
#include <math.h>

// Problem constants (B, T, L, H) = (8, 32, 512, 768)
constexpr int Bn = 8, Tn = 32, Ln = 512, Hn = 768;

// ---------------------------------------------------------------------------
// NT GEMM: C[M,N] = A[M,K] * B[N,K]^T.  64x64 tile, TK=16, 256 threads,
// each thread computes a 4x4 register tile. M,N % 64 == 0, K % 16 == 0.
// ---------------------------------------------------------------------------
__global__ __launch_bounds__(256) void gemm_nt64(
    const float* __restrict__ A,   // [M, K]
    const float* __restrict__ Bm,  // [N, K]
    float* __restrict__ C,         // [M, N]
    int M, int N, int K)
{
    constexpr int TM = 64, TN = 64, TK = 16;
    // +4 pad keeps 16B alignment for float4 LDS reads (stride 68 floats = 17*16B)
    __shared__ float As[TK][TM + 4];  // transposed: As[k][m]
    __shared__ float Bs[TK][TN + 4];

    const int tid = threadIdx.x;
    const int bm = blockIdx.x * TM;
    const int bn = blockIdx.y * TN;
    const int tx = tid & 15;          // output col group
    const int ty = tid >> 4;          // output row group
    const int lr = tid >> 2;          // load row 0..63
    const int lk = (tid & 3) << 2;    // load k offset 0,4,8,12

    float acc[4][4] = {};

    for (int k0 = 0; k0 < K; k0 += TK) {
        const float4 av = *(const float4*)(A  + (size_t)(bm + lr) * K + (k0 + lk));
        const float4 bv = *(const float4*)(Bm + (size_t)(bn + lr) * K + (k0 + lk));
        As[lk + 0][lr] = av.x; As[lk + 1][lr] = av.y;
        As[lk + 2][lr] = av.z; As[lk + 3][lr] = av.w;
        Bs[lk + 0][lr] = bv.x; Bs[lk + 1][lr] = bv.y;
        Bs[lk + 2][lr] = bv.z; Bs[lk + 3][lr] = bv.w;
        __syncthreads();
#pragma unroll
        for (int kk = 0; kk < TK; ++kk) {
            const float4 a = *(const float4*)&As[kk][ty << 2];
            const float4 b = *(const float4*)&Bs[kk][tx << 2];
            const float ar[4] = {a.x, a.y, a.z, a.w};
            const float br[4] = {b.x, b.y, b.z, b.w};
#pragma unroll
            for (int i = 0; i < 4; ++i)
#pragma unroll
                for (int j = 0; j < 4; ++j)
                    acc[i][j] = fmaf(ar[i], br[j], acc[i][j]);
        }
        __syncthreads();
    }

#pragma unroll
    for (int i = 0; i < 4; ++i) {
        float4 o;
        o.x = acc[i][0]; o.y = acc[i][1]; o.z = acc[i][2]; o.w = acc[i][3];
        *(float4*)(C + (size_t)(bm + (ty << 2) + i) * N + bn + (tx << 2)) = o;
    }
}

// ---------------------------------------------------------------------------
// Fused scores + masked log-softmax.  One block per (b,t): 512 threads = 8
// waves.  Each wave computes scores for l = wv, wv+8, ... via a lane-strided
// dot over H with WD/v fragments preloaded into registers; then the block
// does the masked log-softmax over L=512.
// Block swizzle: b = blockIdx.x & 7 -> all 32 t-blocks of a doc land on the
// same XCD (bid % 8 mapping), so WE[b] (1.57 MB) stays hot in that 4MB L2.
// ---------------------------------------------------------------------------
__global__ __launch_bounds__(512) void score_softmax(
    const float* __restrict__ WE,     // [B*L, H]
    const float* __restrict__ WD,     // [B*T, H]
    const float* __restrict__ v,      // [H]
    const int* __restrict__ starts,   // [B*T]
    const int* __restrict__ lens,     // [B]
    float* __restrict__ out)          // [B*T, L]
{
    constexpr float kScale = 1.0507009873554804934193349852946f;  // selu scale
    constexpr float kAS    = 1.7580993408473768f;                 // scale*alpha

    const int bid = blockIdx.x;
    const int b = bid & 7;
    const int t = bid >> 3;
    const int bt = b * Tn + t;
    const int tid = threadIdx.x;
    const int lane = tid & 63;
    const int wv = tid >> 6;  // 0..7

    __shared__ float sc[Ln];
    __shared__ float red[16];

    // Preload this lane's WD and v fragments: h = 4*lane + 256*j, j=0..2
    float4 wdr[3], vr[3];
#pragma unroll
    for (int j = 0; j < 3; ++j) {
        const int h = (lane << 2) + (j << 8);
        wdr[j] = *(const float4*)(WD + (size_t)bt * Hn + h);
        vr[j]  = *(const float4*)(v + h);
    }

    const float* WEb = WE + (size_t)b * Ln * Hn;

    for (int l = wv; l < Ln; l += 8) {
        const float* row = WEb + (size_t)l * Hn;
        float s = 0.f;
#pragma unroll
        for (int j = 0; j < 3; ++j) {
            const int h = (lane << 2) + (j << 8);
            const float4 we = *(const float4*)(row + h);
            {
                const float x = we.x + wdr[j].x;
                const float r = x > 0.f ? kScale * x : fmaf(kAS, __expf(x), -kAS);
                s = fmaf(r, vr[j].x, s);
            }
            {
                const float x = we.y + wdr[j].y;
                const float r = x > 0.f ? kScale * x : fmaf(kAS, __expf(x), -kAS);
                s = fmaf(r, vr[j].y, s);
            }
            {
                const float x = we.z + wdr[j].z;
                const float r = x > 0.f ? kScale * x : fmaf(kAS, __expf(x), -kAS);
                s = fmaf(r, vr[j].z, s);
            }
            {
                const float x = we.w + wdr[j].w;
                const float r = x > 0.f ? kScale * x : fmaf(kAS, __expf(x), -kAS);
                s = fmaf(r, vr[j].w, s);
            }
        }
#pragma unroll
        for (int off = 32; off > 0; off >>= 1)
            s += __shfl_xor(s, off, 64);
        if (lane == 0) {
            // outer selu on the dot result
            sc[l] = s > 0.f ? kScale * s : fmaf(kAS, __expf(s), -kAS);
        }
    }
    __syncthreads();

    // ---- masked log-softmax over L (one thread per l) ----
    const int start = starts[bt];
    const int len = lens[b];
    const int l = tid;                       // blockDim.x == Ln == 512
    const bool msk = (l >= start) && (l < len);
    const float val = sc[l];

    float mx = msk ? val : -1e30f;
#pragma unroll
    for (int off = 32; off > 0; off >>= 1)
        mx = fmaxf(mx, __shfl_xor(mx, off, 64));
    if (lane == 0) red[wv] = mx;
    __syncthreads();
    mx = red[0];
#pragma unroll
    for (int i = 1; i < 8; ++i) mx = fmaxf(mx, red[i]);

    float sm = msk ? __expf(val - mx) : 0.f;
#pragma unroll
    for (int off = 32; off > 0; off >>= 1)
        sm += __shfl_xor(sm, off, 64);
    if (lane == 0) red[8 + wv] = sm;
    __syncthreads();
    float tot = red[8];
#pragma unroll
    for (int i = 1; i < 8; ++i) tot += red[8 + i];

    const float logZ = mx + __logf(tot);
    out[(size_t)bt * Ln + l] = msk ? (val - logZ) : 0.f;
}

// ---------------------------------------------------------------------------
extern "C" void kernel_launch(void* const* d_in, const int* in_sizes, int n_in,
                              void* d_out, int out_size, void* d_ws, size_t ws_size,
                              hipStream_t stream) {
    const float* enc    = (const float*)d_in[0];  // [B, L, H]
    const float* dec    = (const float*)d_in[1];  // [B, T, H]
    const float* W1     = (const float*)d_in[2];  // [H, H]
    const float* W2     = (const float*)d_in[3];  // [H, H]
    const float* v      = (const float*)d_in[4];  // [H]
    const int*   starts = (const int*)d_in[5];    // [B, T]
    const int*   lens   = (const int*)d_in[6];    // [B]
    float* out = (float*)d_out;

    const size_t we_elems = (size_t)Bn * Ln * Hn;   // 3,145,728
    const size_t wd_elems = (size_t)Bn * Tn * Hn;   //   196,608
    if (ws_size < (we_elems + wd_elems) * sizeof(float)) return;  // visible failure

    float* WE = (float*)d_ws;
    float* WD = WE + we_elems;

    gemm_nt64<<<dim3((Bn * Ln) / 64, Hn / 64), dim3(256), 0, stream>>>(
        enc, W1, WE, Bn * Ln, Hn, Hn);
    gemm_nt64<<<dim3((Bn * Tn) / 64, Hn / 64), dim3(256), 0, stream>>>(
        dec, W2, WD, Bn * Tn, Hn, Hn);
    score_softmax<<<dim3(Bn * Tn), dim3(512), 0, stream>>>(
        WE, WD, v, starts, lens, out);
}

// Round 2
// 158.126 us; speedup vs baseline: 1.4693x; 1.4693x over previous
//
#include <hip/hip_runtime.h>
#include <math.h>

// Problem constants (B, T, L, H) = (8, 32, 512, 768)
constexpr int Bn = 8, Tn = 32, Ln = 512, Hn = 768;

typedef __attribute__((ext_vector_type(8))) short bf16x8;   // 8 bf16 = 4 VGPRs
typedef __attribute__((ext_vector_type(4))) float f32x4;

// ---------------------------------------------------------------------------
// fp32 -> bf16 (RNE) for 4 tensors in one launch; each thread does one float4.
// ---------------------------------------------------------------------------
__device__ __forceinline__ short f2bf(float x) {
    unsigned u = __float_as_uint(x);
    u += 0x7FFFu + ((u >> 16) & 1u);
    return (short)(u >> 16);
}

__global__ __launch_bounds__(256) void cvt_bf16_multi(
    const float* __restrict__ s0, short* __restrict__ d0, int c0,   // cumulative float4 counts
    const float* __restrict__ s1, short* __restrict__ d1, int c1,
    const float* __restrict__ s2, short* __restrict__ d2, int c2,
    const float* __restrict__ s3, short* __restrict__ d3, int c3)
{
    const int i = blockIdx.x * 256 + threadIdx.x;
    if (i >= c3) return;
    const float* s; short* d; int off;
    if (i < c0)      { s = s0; d = d0; off = i; }
    else if (i < c1) { s = s1; d = d1; off = i - c0; }
    else if (i < c2) { s = s2; d = d2; off = i - c1; }
    else             { s = s3; d = d3; off = i - c2; }
    const float4 f = ((const float4*)s)[off];
    short4 r;
    r.x = f2bf(f.x); r.y = f2bf(f.y); r.z = f2bf(f.z); r.w = f2bf(f.w);
    ((short4*)d)[off] = r;
}

// ---------------------------------------------------------------------------
// bf16 NT MFMA GEMM: C[M,N] = A[M,K] * B[N,K]^T, fp32 out.
// BM=128, BN=64, BK=32, 256 threads = 4 waves; each wave computes a 64x32
// quadrant as 4x2 MFMA 16x16x32 tiles.  Staging via global_load_lds width=16.
// M % 128 == 0, N % 64 == 0, K % 32 == 0.
// ---------------------------------------------------------------------------
__global__ __launch_bounds__(256) void gemm_bf16_nt(
    const short* __restrict__ A,   // [M, K] bf16
    const short* __restrict__ Bm,  // [N, K] bf16
    float* __restrict__ C,         // [M, N] fp32
    int M, int N, int K)
{
    constexpr int BM = 128, BN = 64, BK = 32;
    __shared__ __align__(16) short As[BM * BK];
    __shared__ __align__(16) short Bs[BN * BK];

    const int tid  = threadIdx.x;
    const int lane = tid & 63;
    const int wv   = tid >> 6;          // 0..3
    const int quad = lane >> 4;         // 0..3
    const int l16  = lane & 15;
    const int wm   = (wv & 1) * 64;     // wave row offset in tile
    const int wn   = (wv >> 1) * 32;    // wave col offset in tile
    const int bm   = blockIdx.x * BM;
    const int bn   = blockIdx.y * BN;

    // staging lane assignment: row chunk of 16 rows per wave, 4 x 16B per row
    const int sr = lane >> 2;           // 0..15 row within chunk
    const int kq = (lane & 3) << 3;     // k elem offset: 0,8,16,24

    f32x4 acc[4][2] = {};

    for (int k0 = 0; k0 < K; k0 += BK) {
        // A tile: rows 0..127 (two 64-row halves), lds dest = wv*1024 + lane*16 bytes
        {
            const int ra = wv * 16 + sr;
            __builtin_amdgcn_global_load_lds(
                (const __attribute__((address_space(1))) unsigned int*)(A + (size_t)(bm + ra) * K + k0 + kq),
                (__attribute__((address_space(3))) unsigned int*)(As + ra * BK + kq),
                16, 0, 0);
            __builtin_amdgcn_global_load_lds(
                (const __attribute__((address_space(1))) unsigned int*)(A + (size_t)(bm + 64 + ra) * K + k0 + kq),
                (__attribute__((address_space(3))) unsigned int*)(As + (64 + ra) * BK + kq),
                16, 0, 0);
            __builtin_amdgcn_global_load_lds(
                (const __attribute__((address_space(1))) unsigned int*)(Bm + (size_t)(bn + ra) * K + k0 + kq),
                (__attribute__((address_space(3))) unsigned int*)(Bs + ra * BK + kq),
                16, 0, 0);
        }
        __syncthreads();

        bf16x8 af[4], bfr[2];
#pragma unroll
        for (int i = 0; i < 4; ++i)
            af[i] = *(const bf16x8*)&As[(wm + i * 16 + l16) * BK + quad * 8];
#pragma unroll
        for (int j = 0; j < 2; ++j)
            bfr[j] = *(const bf16x8*)&Bs[(wn + j * 16 + l16) * BK + quad * 8];
#pragma unroll
        for (int i = 0; i < 4; ++i)
#pragma unroll
            for (int j = 0; j < 2; ++j)
                acc[i][j] = __builtin_amdgcn_mfma_f32_16x16x32_bf16(af[i], bfr[j], acc[i][j], 0, 0, 0);
        __syncthreads();
    }

    // Epilogue: D mapping col = lane&15, row = quad*4 + rr
#pragma unroll
    for (int i = 0; i < 4; ++i)
#pragma unroll
        for (int j = 0; j < 2; ++j)
#pragma unroll
            for (int rr = 0; rr < 4; ++rr) {
                const int row = bm + wm + i * 16 + quad * 4 + rr;
                const int col = bn + wn + j * 16 + l16;
                C[(size_t)row * N + col] = acc[i][j][rr];
            }
}

// ---------------------------------------------------------------------------
// Fused scores + masked log-softmax (unchanged from R1).
// ---------------------------------------------------------------------------
__global__ __launch_bounds__(512) void score_softmax(
    const float* __restrict__ WE,     // [B*L, H]
    const float* __restrict__ WD,     // [B*T, H]
    const float* __restrict__ v,      // [H]
    const int* __restrict__ starts,   // [B*T]
    const int* __restrict__ lens,     // [B]
    float* __restrict__ out)          // [B*T, L]
{
    constexpr float kScale = 1.0507009873554804934193349852946f;  // selu scale
    constexpr float kAS    = 1.7580993408473768f;                 // scale*alpha

    const int bid = blockIdx.x;
    const int b = bid & 7;
    const int t = bid >> 3;
    const int bt = b * Tn + t;
    const int tid = threadIdx.x;
    const int lane = tid & 63;
    const int wv = tid >> 6;  // 0..7

    __shared__ float sc[Ln];
    __shared__ float red[16];

    float4 wdr[3], vr[3];
#pragma unroll
    for (int j = 0; j < 3; ++j) {
        const int h = (lane << 2) + (j << 8);
        wdr[j] = *(const float4*)(WD + (size_t)bt * Hn + h);
        vr[j]  = *(const float4*)(v + h);
    }

    const float* WEb = WE + (size_t)b * Ln * Hn;

    for (int l = wv; l < Ln; l += 8) {
        const float* row = WEb + (size_t)l * Hn;
        float s = 0.f;
#pragma unroll
        for (int j = 0; j < 3; ++j) {
            const int h = (lane << 2) + (j << 8);
            const float4 we = *(const float4*)(row + h);
            {
                const float x = we.x + wdr[j].x;
                const float r = x > 0.f ? kScale * x : fmaf(kAS, __expf(x), -kAS);
                s = fmaf(r, vr[j].x, s);
            }
            {
                const float x = we.y + wdr[j].y;
                const float r = x > 0.f ? kScale * x : fmaf(kAS, __expf(x), -kAS);
                s = fmaf(r, vr[j].y, s);
            }
            {
                const float x = we.z + wdr[j].z;
                const float r = x > 0.f ? kScale * x : fmaf(kAS, __expf(x), -kAS);
                s = fmaf(r, vr[j].z, s);
            }
            {
                const float x = we.w + wdr[j].w;
                const float r = x > 0.f ? kScale * x : fmaf(kAS, __expf(x), -kAS);
                s = fmaf(r, vr[j].w, s);
            }
        }
#pragma unroll
        for (int off = 32; off > 0; off >>= 1)
            s += __shfl_xor(s, off, 64);
        if (lane == 0) {
            sc[l] = s > 0.f ? kScale * s : fmaf(kAS, __expf(s), -kAS);
        }
    }
    __syncthreads();

    const int start = starts[bt];
    const int len = lens[b];
    const int l = tid;                       // blockDim.x == Ln == 512
    const bool msk = (l >= start) && (l < len);
    const float val = sc[l];

    float mx = msk ? val : -1e30f;
#pragma unroll
    for (int off = 32; off > 0; off >>= 1)
        mx = fmaxf(mx, __shfl_xor(mx, off, 64));
    if (lane == 0) red[wv] = mx;
    __syncthreads();
    mx = red[0];
#pragma unroll
    for (int i = 1; i < 8; ++i) mx = fmaxf(mx, red[i]);

    float sm = msk ? __expf(val - mx) : 0.f;
#pragma unroll
    for (int off = 32; off > 0; off >>= 1)
        sm += __shfl_xor(sm, off, 64);
    if (lane == 0) red[8 + wv] = sm;
    __syncthreads();
    float tot = red[8];
#pragma unroll
    for (int i = 1; i < 8; ++i) tot += red[8 + i];

    const float logZ = mx + __logf(tot);
    out[(size_t)bt * Ln + l] = msk ? (val - logZ) : 0.f;
}

// ---------------------------------------------------------------------------
extern "C" void kernel_launch(void* const* d_in, const int* in_sizes, int n_in,
                              void* d_out, int out_size, void* d_ws, size_t ws_size,
                              hipStream_t stream) {
    const float* enc    = (const float*)d_in[0];  // [B, L, H]
    const float* dec    = (const float*)d_in[1];  // [B, T, H]
    const float* W1     = (const float*)d_in[2];  // [H, H]
    const float* W2     = (const float*)d_in[3];  // [H, H]
    const float* v      = (const float*)d_in[4];  // [H]
    const int*   starts = (const int*)d_in[5];    // [B, T]
    const int*   lens   = (const int*)d_in[6];    // [B]
    float* out = (float*)d_out;

    constexpr int n_enc = Bn * Ln * Hn;   // 3,145,728
    constexpr int n_dec = Bn * Tn * Hn;   //   196,608
    constexpr int n_w   = Hn * Hn;        //   589,824

    const size_t need = (size_t)(n_enc + n_dec + 2 * n_w) * 2   // bf16 copies
                      + (size_t)(n_enc + n_dec) * 4;            // WE + WD fp32
    if (ws_size < need) return;  // visible failure

    short* enc16 = (short*)d_ws;
    short* dec16 = enc16 + n_enc;
    short* w1_16 = dec16 + n_dec;
    short* w2_16 = w1_16 + n_w;
    float* WE    = (float*)(w2_16 + n_w);
    float* WD    = WE + n_enc;

    // cumulative float4 counts
    constexpr int c0 = n_enc / 4;
    constexpr int c1 = c0 + n_dec / 4;
    constexpr int c2 = c1 + n_w / 4;
    constexpr int c3 = c2 + n_w / 4;
    cvt_bf16_multi<<<dim3((c3 + 255) / 256), dim3(256), 0, stream>>>(
        enc, enc16, c0, dec, dec16, c1, W1, w1_16, c2, W2, w2_16, c3);

    gemm_bf16_nt<<<dim3((Bn * Ln) / 128, Hn / 64), dim3(256), 0, stream>>>(
        enc16, w1_16, WE, Bn * Ln, Hn, Hn);
    gemm_bf16_nt<<<dim3((Bn * Tn) / 128, Hn / 64), dim3(256), 0, stream>>>(
        dec16, w2_16, WD, Bn * Tn, Hn, Hn);

    score_softmax<<<dim3(Bn * Tn), dim3(512), 0, stream>>>(
        WE, WD, v, starts, lens, out);
}

// Round 3
// 139.601 us; speedup vs baseline: 1.6642x; 1.1327x over previous
//
#include <hip/hip_runtime.h>
#include <math.h>

// Problem constants (B, T, L, H) = (8, 32, 512, 768)
constexpr int Bn = 8, Tn = 32, Ln = 512, Hn = 768;

typedef __attribute__((ext_vector_type(8))) short bf16x8;   // 8 bf16 = 4 VGPRs
typedef __attribute__((ext_vector_type(4))) float f32x4;

__device__ __forceinline__ short f2bf(float x) {
    unsigned u = __float_as_uint(x);
    u += 0x7FFFu + ((u >> 16) & 1u);
    return (short)(u >> 16);
}
__device__ __forceinline__ float bf2f(unsigned short s) {
    return __uint_as_float(((unsigned)s) << 16);
}

// selu constants
constexpr float kScale = 1.0507009873554804934193349852946f;
constexpr float kAS    = 1.7580993408473768f;   // scale * alpha

__device__ __forceinline__ float selu(float x) {
    return x > 0.f ? kScale * x : fmaf(kAS, __expf(x), -kAS);
}

// ---------------------------------------------------------------------------
// fp32 -> bf16 (RNE) for 4 tensors in one launch; each thread does one float4.
// ---------------------------------------------------------------------------
__global__ __launch_bounds__(256) void cvt_bf16_multi(
    const float* __restrict__ s0, short* __restrict__ d0, int c0,   // cumulative float4 counts
    const float* __restrict__ s1, short* __restrict__ d1, int c1,
    const float* __restrict__ s2, short* __restrict__ d2, int c2,
    const float* __restrict__ s3, short* __restrict__ d3, int c3)
{
    const int i = blockIdx.x * 256 + threadIdx.x;
    if (i >= c3) return;
    const float* s; short* d; int off;
    if (i < c0)      { s = s0; d = d0; off = i; }
    else if (i < c1) { s = s1; d = d1; off = i - c0; }
    else if (i < c2) { s = s2; d = d2; off = i - c1; }
    else             { s = s3; d = d3; off = i - c2; }
    const float4 f = ((const float4*)s)[off];
    short4 r;
    r.x = f2bf(f.x); r.y = f2bf(f.y); r.z = f2bf(f.z); r.w = f2bf(f.w);
    ((short4*)d)[off] = r;
}

// ---------------------------------------------------------------------------
// bf16 NT MFMA GEMM: C[M,N] = A[M,K] * B[N,K]^T, bf16 out.
// BM=128, BN=64, BK=32, 256 threads = 4 waves.
// ---------------------------------------------------------------------------
__global__ __launch_bounds__(256) void gemm_bf16_nt(
    const short* __restrict__ A,   // [M, K] bf16
    const short* __restrict__ Bm,  // [N, K] bf16
    unsigned short* __restrict__ C,// [M, N] bf16
    int M, int N, int K)
{
    constexpr int BM = 128, BN = 64, BK = 32;
    __shared__ __align__(16) short As[BM * BK];
    __shared__ __align__(16) short Bs[BN * BK];

    const int tid  = threadIdx.x;
    const int lane = tid & 63;
    const int wv   = tid >> 6;          // 0..3
    const int quad = lane >> 4;         // 0..3
    const int l16  = lane & 15;
    const int wm   = (wv & 1) * 64;
    const int wn   = (wv >> 1) * 32;
    const int bm   = blockIdx.x * BM;
    const int bn   = blockIdx.y * BN;

    const int sr = lane >> 2;           // 0..15 row within chunk
    const int kq = (lane & 3) << 3;     // k elem offset: 0,8,16,24

    f32x4 acc[4][2] = {};

    for (int k0 = 0; k0 < K; k0 += BK) {
        {
            const int ra = wv * 16 + sr;
            __builtin_amdgcn_global_load_lds(
                (const __attribute__((address_space(1))) unsigned int*)(A + (size_t)(bm + ra) * K + k0 + kq),
                (__attribute__((address_space(3))) unsigned int*)(As + ra * BK + kq),
                16, 0, 0);
            __builtin_amdgcn_global_load_lds(
                (const __attribute__((address_space(1))) unsigned int*)(A + (size_t)(bm + 64 + ra) * K + k0 + kq),
                (__attribute__((address_space(3))) unsigned int*)(As + (64 + ra) * BK + kq),
                16, 0, 0);
            __builtin_amdgcn_global_load_lds(
                (const __attribute__((address_space(1))) unsigned int*)(Bm + (size_t)(bn + ra) * K + k0 + kq),
                (__attribute__((address_space(3))) unsigned int*)(Bs + ra * BK + kq),
                16, 0, 0);
        }
        __syncthreads();

        bf16x8 af[4], bfr[2];
#pragma unroll
        for (int i = 0; i < 4; ++i)
            af[i] = *(const bf16x8*)&As[(wm + i * 16 + l16) * BK + quad * 8];
#pragma unroll
        for (int j = 0; j < 2; ++j)
            bfr[j] = *(const bf16x8*)&Bs[(wn + j * 16 + l16) * BK + quad * 8];
#pragma unroll
        for (int i = 0; i < 4; ++i)
#pragma unroll
            for (int j = 0; j < 2; ++j)
                acc[i][j] = __builtin_amdgcn_mfma_f32_16x16x32_bf16(af[i], bfr[j], acc[i][j], 0, 0, 0);
        __syncthreads();
    }

    // Epilogue: D mapping col = lane&15, row = quad*4 + rr ; store bf16
#pragma unroll
    for (int i = 0; i < 4; ++i)
#pragma unroll
        for (int j = 0; j < 2; ++j)
#pragma unroll
            for (int rr = 0; rr < 4; ++rr) {
                const int row = bm + wm + i * 16 + quad * 4 + rr;
                const int col = bn + wn + j * 16 + l16;
                C[(size_t)row * N + col] = (unsigned short)f2bf(acc[i][j][rr]);
            }
}

// ---------------------------------------------------------------------------
// Scores: sc[bt, l] = selu( sum_h selu(WE[b,l,h] + WD[bt,h]) * v[h] )
// Grid: 2048 blocks x 256 threads (4 waves). Block -> (b = bid&7 for XCD-L2
// locality of WE[b], t, l-chunk of 64). Each wave computes 16 l-rows.
// ---------------------------------------------------------------------------
__global__ __launch_bounds__(256) void scores_kernel(
    const unsigned short* __restrict__ WE,  // [B*L, H] bf16
    const unsigned short* __restrict__ WD,  // [B*T, H] bf16
    const float* __restrict__ v,            // [H]
    float* __restrict__ sc)                 // [B*T, L]
{
    const int bid = blockIdx.x;
    const int b = bid & 7;
    const int r = bid >> 3;        // 0..255
    const int t = r & 31;
    const int chunk = r >> 5;      // 0..7
    const int bt = b * Tn + t;
    const int lane = threadIdx.x & 63;
    const int wv = threadIdx.x >> 6;       // 0..3
    const int l0 = chunk * 64 + wv * 16;

    // Per-lane fragments of WD row and v: h = 4*lane + 256*j
    float wdr[12], vr[12];
#pragma unroll
    for (int j = 0; j < 3; ++j) {
        const int h = (lane << 2) + (j << 8);
        const ushort4 wdu = *(const ushort4*)(WD + (size_t)bt * Hn + h);
        const float4 vv = *(const float4*)(v + h);
        wdr[j * 4 + 0] = bf2f(wdu.x); wdr[j * 4 + 1] = bf2f(wdu.y);
        wdr[j * 4 + 2] = bf2f(wdu.z); wdr[j * 4 + 3] = bf2f(wdu.w);
        vr[j * 4 + 0] = vv.x; vr[j * 4 + 1] = vv.y;
        vr[j * 4 + 2] = vv.z; vr[j * 4 + 3] = vv.w;
    }

    const unsigned short* WEb = WE + (size_t)b * Ln * Hn;

    for (int i = 0; i < 16; ++i) {
        const int l = l0 + i;
        const unsigned short* row = WEb + (size_t)l * Hn;
        float s = 0.f;
#pragma unroll
        for (int j = 0; j < 3; ++j) {
            const int h = (lane << 2) + (j << 8);
            const ushort4 weu = *(const ushort4*)(row + h);
            float x;
            x = bf2f(weu.x) + wdr[j * 4 + 0]; s = fmaf(selu(x), vr[j * 4 + 0], s);
            x = bf2f(weu.y) + wdr[j * 4 + 1]; s = fmaf(selu(x), vr[j * 4 + 1], s);
            x = bf2f(weu.z) + wdr[j * 4 + 2]; s = fmaf(selu(x), vr[j * 4 + 2], s);
            x = bf2f(weu.w) + wdr[j * 4 + 3]; s = fmaf(selu(x), vr[j * 4 + 3], s);
        }
#pragma unroll
        for (int off = 32; off > 0; off >>= 1)
            s += __shfl_xor(s, off, 64);
        if (lane == 0)
            sc[(size_t)bt * Ln + l] = selu(s);
    }
}

// ---------------------------------------------------------------------------
// Masked log-softmax over L=512. One block per bt, 512 threads.
// ---------------------------------------------------------------------------
__global__ __launch_bounds__(512) void softmax_kernel(
    const float* __restrict__ sc,     // [B*T, L]
    const int* __restrict__ starts,   // [B*T]
    const int* __restrict__ lens,     // [B]
    float* __restrict__ out)          // [B*T, L]
{
    __shared__ float red[16];
    const int bt = blockIdx.x;
    const int b = bt / Tn;
    const int tid = threadIdx.x;
    const int lane = tid & 63;
    const int wv = tid >> 6;

    const int start = starts[bt];
    const int len = lens[b];
    const int l = tid;
    const bool msk = (l >= start) && (l < len);
    const float val = sc[(size_t)bt * Ln + l];

    float mx = msk ? val : -1e30f;
#pragma unroll
    for (int off = 32; off > 0; off >>= 1)
        mx = fmaxf(mx, __shfl_xor(mx, off, 64));
    if (lane == 0) red[wv] = mx;
    __syncthreads();
    mx = red[0];
#pragma unroll
    for (int i = 1; i < 8; ++i) mx = fmaxf(mx, red[i]);

    float sm = msk ? __expf(val - mx) : 0.f;
#pragma unroll
    for (int off = 32; off > 0; off >>= 1)
        sm += __shfl_xor(sm, off, 64);
    if (lane == 0) red[8 + wv] = sm;
    __syncthreads();
    float tot = red[8];
#pragma unroll
    for (int i = 1; i < 8; ++i) tot += red[8 + i];

    const float logZ = mx + __logf(tot);
    out[(size_t)bt * Ln + l] = msk ? (val - logZ) : 0.f;
}

// ---------------------------------------------------------------------------
extern "C" void kernel_launch(void* const* d_in, const int* in_sizes, int n_in,
                              void* d_out, int out_size, void* d_ws, size_t ws_size,
                              hipStream_t stream) {
    const float* enc    = (const float*)d_in[0];  // [B, L, H]
    const float* dec    = (const float*)d_in[1];  // [B, T, H]
    const float* W1     = (const float*)d_in[2];  // [H, H]
    const float* W2     = (const float*)d_in[3];  // [H, H]
    const float* v      = (const float*)d_in[4];  // [H]
    const int*   starts = (const int*)d_in[5];    // [B, T]
    const int*   lens   = (const int*)d_in[6];    // [B]
    float* out = (float*)d_out;

    constexpr int n_enc = Bn * Ln * Hn;   // 3,145,728
    constexpr int n_dec = Bn * Tn * Hn;   //   196,608
    constexpr int n_w   = Hn * Hn;        //   589,824
    constexpr int n_sc  = Bn * Tn * Ln;   //   131,072

    const size_t need = (size_t)(n_enc + n_dec + 2 * n_w) * 2   // bf16 inputs
                      + (size_t)(n_enc + n_dec) * 2             // WE16 + WD16
                      + (size_t)n_sc * 4;                       // sc fp32
    if (ws_size < need) return;  // visible failure

    short* enc16 = (short*)d_ws;
    short* dec16 = enc16 + n_enc;
    short* w1_16 = dec16 + n_dec;
    short* w2_16 = w1_16 + n_w;
    unsigned short* WE16 = (unsigned short*)(w2_16 + n_w);
    unsigned short* WD16 = WE16 + n_enc;
    float* sc = (float*)(WD16 + n_dec);

    constexpr int c0 = n_enc / 4;
    constexpr int c1 = c0 + n_dec / 4;
    constexpr int c2 = c1 + n_w / 4;
    constexpr int c3 = c2 + n_w / 4;
    cvt_bf16_multi<<<dim3((c3 + 255) / 256), dim3(256), 0, stream>>>(
        enc, enc16, c0, dec, dec16, c1, W1, w1_16, c2, W2, w2_16, c3);

    gemm_bf16_nt<<<dim3((Bn * Ln) / 128, Hn / 64), dim3(256), 0, stream>>>(
        enc16, w1_16, WE16, Bn * Ln, Hn, Hn);
    gemm_bf16_nt<<<dim3((Bn * Tn) / 128, Hn / 64), dim3(256), 0, stream>>>(
        dec16, w2_16, WD16, Bn * Tn, Hn, Hn);

    scores_kernel<<<dim3(2048), dim3(256), 0, stream>>>(WE16, WD16, v, sc);
    softmax_kernel<<<dim3(Bn * Tn), dim3(512), 0, stream>>>(sc, starts, lens, out);
}

// Round 4
// 130.354 us; speedup vs baseline: 1.7823x; 1.0709x over previous
//
#include <hip/hip_runtime.h>
#include <math.h>

// Problem constants (B, T, L, H) = (8, 32, 512, 768)
constexpr int Bn = 8, Tn = 32, Ln = 512, Hn = 768;

typedef __attribute__((ext_vector_type(8))) short bf16x8;   // 8 bf16 = 4 VGPRs
typedef __attribute__((ext_vector_type(4))) float f32x4;

__device__ __forceinline__ short f2bf(float x) {
    unsigned u = __float_as_uint(x);
    u += 0x7FFFu + ((u >> 16) & 1u);
    return (short)(u >> 16);
}
__device__ __forceinline__ float bf2f(unsigned short s) {
    return __uint_as_float(((unsigned)s) << 16);
}

// selu constants
constexpr float kScale = 1.0507009873554804934193349852946f;
constexpr float kAS    = 1.7580993408473768f;   // scale * alpha

__device__ __forceinline__ float selu(float x) {
    return x > 0.f ? kScale * x : fmaf(kAS, __expf(x), -kAS);
}

// ---------------------------------------------------------------------------
// fp32 -> bf16 (RNE) for 4 tensors in one launch; each thread does one float4.
// ---------------------------------------------------------------------------
__global__ __launch_bounds__(256) void cvt_bf16_multi(
    const float* __restrict__ s0, short* __restrict__ d0, int c0,   // cumulative float4 counts
    const float* __restrict__ s1, short* __restrict__ d1, int c1,
    const float* __restrict__ s2, short* __restrict__ d2, int c2,
    const float* __restrict__ s3, short* __restrict__ d3, int c3)
{
    const int i = blockIdx.x * 256 + threadIdx.x;
    if (i >= c3) return;
    const float* s; short* d; int off;
    if (i < c0)      { s = s0; d = d0; off = i; }
    else if (i < c1) { s = s1; d = d1; off = i - c0; }
    else if (i < c2) { s = s2; d = d2; off = i - c1; }
    else             { s = s3; d = d3; off = i - c2; }
    const float4 f = ((const float4*)s)[off];
    short4 r;
    r.x = f2bf(f.x); r.y = f2bf(f.y); r.z = f2bf(f.z); r.w = f2bf(f.w);
    ((short4*)d)[off] = r;
}

// ---------------------------------------------------------------------------
// Merged bf16 NT MFMA GEMM for both WE and WD in ONE launch.
// C[M,N] = A[M,K] * B[N,K]^T, bf16 out.  BM=BN=128, BK=32, 256 threads =
// 4 waves in 2x2; each wave computes 64x64 = 4x4 MFMA 16x16x32 tiles
// (16 MFMA per K-step per wave, m97 structure).  Staging via
// global_load_lds width=16 (LDS dest == wave-uniform base + lane*16).
// blockIdx.x < M1/128 -> problem 1 (WE), else problem 2 (WD).
// ---------------------------------------------------------------------------
__global__ __launch_bounds__(256) void gemm2_bf16_nt(
    const short* __restrict__ A1, const short* __restrict__ B1,
    unsigned short* __restrict__ C1, int M1,
    const short* __restrict__ A2, const short* __restrict__ B2,
    unsigned short* __restrict__ C2,
    int N, int K)
{
    constexpr int BM = 128, BN = 128, BK = 32;
    __shared__ __align__(16) short As[BM * BK];
    __shared__ __align__(16) short Bs[BN * BK];

    const int nblk1 = M1 / BM;
    const int bx = blockIdx.x;
    const short* A; const short* Bm; unsigned short* C; int bm;
    if (bx < nblk1) { A = A1; Bm = B1; C = C1; bm = bx * BM; }
    else            { A = A2; Bm = B2; C = C2; bm = (bx - nblk1) * BM; }
    const int bn = blockIdx.y * BN;

    const int tid  = threadIdx.x;
    const int lane = tid & 63;
    const int wv   = tid >> 6;          // 0..3
    const int quad = lane >> 4;         // 0..3
    const int l16  = lane & 15;
    const int wm   = (wv & 1) * 64;
    const int wn   = (wv >> 1) * 64;

    const int sr = lane >> 2;           // 0..15 row within 16-row chunk
    const int kq = (lane & 3) << 3;     // k elem offset: 0,8,16,24

    f32x4 acc[4][4] = {};

    for (int k0 = 0; k0 < K; k0 += BK) {
        const int ra = wv * 16 + sr;    // 0..63
        __builtin_amdgcn_global_load_lds(
            (const __attribute__((address_space(1))) unsigned int*)(A + (size_t)(bm + ra) * K + k0 + kq),
            (__attribute__((address_space(3))) unsigned int*)(As + ra * BK + kq), 16, 0, 0);
        __builtin_amdgcn_global_load_lds(
            (const __attribute__((address_space(1))) unsigned int*)(A + (size_t)(bm + 64 + ra) * K + k0 + kq),
            (__attribute__((address_space(3))) unsigned int*)(As + (64 + ra) * BK + kq), 16, 0, 0);
        __builtin_amdgcn_global_load_lds(
            (const __attribute__((address_space(1))) unsigned int*)(Bm + (size_t)(bn + ra) * K + k0 + kq),
            (__attribute__((address_space(3))) unsigned int*)(Bs + ra * BK + kq), 16, 0, 0);
        __builtin_amdgcn_global_load_lds(
            (const __attribute__((address_space(1))) unsigned int*)(Bm + (size_t)(bn + 64 + ra) * K + k0 + kq),
            (__attribute__((address_space(3))) unsigned int*)(Bs + (64 + ra) * BK + kq), 16, 0, 0);
        __syncthreads();

        bf16x8 af[4], bfr[4];
#pragma unroll
        for (int i = 0; i < 4; ++i)
            af[i] = *(const bf16x8*)&As[(wm + i * 16 + l16) * BK + quad * 8];
#pragma unroll
        for (int j = 0; j < 4; ++j)
            bfr[j] = *(const bf16x8*)&Bs[(wn + j * 16 + l16) * BK + quad * 8];
#pragma unroll
        for (int i = 0; i < 4; ++i)
#pragma unroll
            for (int j = 0; j < 4; ++j)
                acc[i][j] = __builtin_amdgcn_mfma_f32_16x16x32_bf16(af[i], bfr[j], acc[i][j], 0, 0, 0);
        __syncthreads();
    }

    // Epilogue: D mapping col = lane&15, row = quad*4 + rr ; store bf16
#pragma unroll
    for (int i = 0; i < 4; ++i)
#pragma unroll
        for (int j = 0; j < 4; ++j)
#pragma unroll
            for (int rr = 0; rr < 4; ++rr) {
                const int row = bm + wm + i * 16 + quad * 4 + rr;
                const int col = bn + wn + j * 16 + l16;
                C[(size_t)row * N + col] = (unsigned short)f2bf(acc[i][j][rr]);
            }
}

// ---------------------------------------------------------------------------
// Scores: sc[bt, l] = selu( sum_h selu(WE[b,l,h] + WD[bt,h]) * v[h] )
// Grid: 2048 blocks x 256 threads (4 waves) -> 32 waves/CU.  Each wave owns
// 16 l-rows, processed in 4 GROUPS OF 4 so the fma chains and the 6-level
// shuffle reductions run as 4 independent chains (ILP against ds_bpermute
// and exp latency).  b = bid&7 keeps WE[b] hot in one XCD's L2.
// ---------------------------------------------------------------------------
__global__ __launch_bounds__(256) void scores_kernel(
    const unsigned short* __restrict__ WE,  // [B*L, H] bf16
    const unsigned short* __restrict__ WD,  // [B*T, H] bf16
    const float* __restrict__ v,            // [H]
    float* __restrict__ sc)                 // [B*T, L]
{
    const int bid = blockIdx.x;
    const int b = bid & 7;
    const int r = bid >> 3;        // 0..255
    const int t = r & 31;
    const int chunk = r >> 5;      // 0..7
    const int bt = b * Tn + t;
    const int lane = threadIdx.x & 63;
    const int wv = threadIdx.x >> 6;       // 0..3
    const int l0 = chunk * 64 + wv * 16;

    // Per-lane fragments of WD row and v: h = 4*lane + 256*j
    float wdr[12], vr[12];
#pragma unroll
    for (int j = 0; j < 3; ++j) {
        const int h = (lane << 2) + (j << 8);
        const ushort4 wdu = *(const ushort4*)(WD + (size_t)bt * Hn + h);
        const float4 vv = *(const float4*)(v + h);
        wdr[j * 4 + 0] = bf2f(wdu.x); wdr[j * 4 + 1] = bf2f(wdu.y);
        wdr[j * 4 + 2] = bf2f(wdu.z); wdr[j * 4 + 3] = bf2f(wdu.w);
        vr[j * 4 + 0] = vv.x; vr[j * 4 + 1] = vv.y;
        vr[j * 4 + 2] = vv.z; vr[j * 4 + 3] = vv.w;
    }

    const unsigned short* WEb = WE + (size_t)b * Ln * Hn;

#pragma unroll
    for (int g = 0; g < 4; ++g) {
        const int lg = l0 + g * 4;
        // issue all 12 loads up front (independent)
        ushort4 weu[4][3];
#pragma unroll
        for (int rr = 0; rr < 4; ++rr) {
            const unsigned short* row = WEb + (size_t)(lg + rr) * Hn;
#pragma unroll
            for (int j = 0; j < 3; ++j)
                weu[rr][j] = *(const ushort4*)(row + (lane << 2) + (j << 8));
        }
        float s[4] = {0.f, 0.f, 0.f, 0.f};
#pragma unroll
        for (int j = 0; j < 3; ++j) {
#pragma unroll
            for (int rr = 0; rr < 4; ++rr) {   // 4 independent chains
                float x;
                x = bf2f(weu[rr][j].x) + wdr[j * 4 + 0]; s[rr] = fmaf(selu(x), vr[j * 4 + 0], s[rr]);
                x = bf2f(weu[rr][j].y) + wdr[j * 4 + 1]; s[rr] = fmaf(selu(x), vr[j * 4 + 1], s[rr]);
                x = bf2f(weu[rr][j].z) + wdr[j * 4 + 2]; s[rr] = fmaf(selu(x), vr[j * 4 + 2], s[rr]);
                x = bf2f(weu[rr][j].w) + wdr[j * 4 + 3]; s[rr] = fmaf(selu(x), vr[j * 4 + 3], s[rr]);
            }
        }
        // 4 interleaved shuffle-reduce trees
#pragma unroll
        for (int off = 32; off > 0; off >>= 1) {
#pragma unroll
            for (int rr = 0; rr < 4; ++rr)
                s[rr] += __shfl_xor(s[rr], off, 64);
        }
        if (lane == 0) {
#pragma unroll
            for (int rr = 0; rr < 4; ++rr)
                sc[(size_t)bt * Ln + lg + rr] = selu(s[rr]);
        }
    }
}

// ---------------------------------------------------------------------------
// Masked log-softmax over L=512. One block per bt, 512 threads.
// ---------------------------------------------------------------------------
__global__ __launch_bounds__(512) void softmax_kernel(
    const float* __restrict__ sc,     // [B*T, L]
    const int* __restrict__ starts,   // [B*T]
    const int* __restrict__ lens,     // [B]
    float* __restrict__ out)          // [B*T, L]
{
    __shared__ float red[16];
    const int bt = blockIdx.x;
    const int b = bt / Tn;
    const int tid = threadIdx.x;
    const int lane = tid & 63;
    const int wv = tid >> 6;

    const int start = starts[bt];
    const int len = lens[b];
    const int l = tid;
    const bool msk = (l >= start) && (l < len);
    const float val = sc[(size_t)bt * Ln + l];

    float mx = msk ? val : -1e30f;
#pragma unroll
    for (int off = 32; off > 0; off >>= 1)
        mx = fmaxf(mx, __shfl_xor(mx, off, 64));
    if (lane == 0) red[wv] = mx;
    __syncthreads();
    mx = red[0];
#pragma unroll
    for (int i = 1; i < 8; ++i) mx = fmaxf(mx, red[i]);

    float sm = msk ? __expf(val - mx) : 0.f;
#pragma unroll
    for (int off = 32; off > 0; off >>= 1)
        sm += __shfl_xor(sm, off, 64);
    if (lane == 0) red[8 + wv] = sm;
    __syncthreads();
    float tot = red[8];
#pragma unroll
    for (int i = 1; i < 8; ++i) tot += red[8 + i];

    const float logZ = mx + __logf(tot);
    out[(size_t)bt * Ln + l] = msk ? (val - logZ) : 0.f;
}

// ---------------------------------------------------------------------------
extern "C" void kernel_launch(void* const* d_in, const int* in_sizes, int n_in,
                              void* d_out, int out_size, void* d_ws, size_t ws_size,
                              hipStream_t stream) {
    const float* enc    = (const float*)d_in[0];  // [B, L, H]
    const float* dec    = (const float*)d_in[1];  // [B, T, H]
    const float* W1     = (const float*)d_in[2];  // [H, H]
    const float* W2     = (const float*)d_in[3];  // [H, H]
    const float* v      = (const float*)d_in[4];  // [H]
    const int*   starts = (const int*)d_in[5];    // [B, T]
    const int*   lens   = (const int*)d_in[6];    // [B]
    float* out = (float*)d_out;

    constexpr int n_enc = Bn * Ln * Hn;   // 3,145,728
    constexpr int n_dec = Bn * Tn * Hn;   //   196,608
    constexpr int n_w   = Hn * Hn;        //   589,824
    constexpr int n_sc  = Bn * Tn * Ln;   //   131,072

    const size_t need = (size_t)(n_enc + n_dec + 2 * n_w) * 2   // bf16 inputs
                      + (size_t)(n_enc + n_dec) * 2             // WE16 + WD16
                      + (size_t)n_sc * 4;                       // sc fp32
    if (ws_size < need) return;  // visible failure

    short* enc16 = (short*)d_ws;
    short* dec16 = enc16 + n_enc;
    short* w1_16 = dec16 + n_dec;
    short* w2_16 = w1_16 + n_w;
    unsigned short* WE16 = (unsigned short*)(w2_16 + n_w);
    unsigned short* WD16 = WE16 + n_enc;
    float* sc = (float*)(WD16 + n_dec);

    constexpr int c0 = n_enc / 4;
    constexpr int c1 = c0 + n_dec / 4;
    constexpr int c2 = c1 + n_w / 4;
    constexpr int c3 = c2 + n_w / 4;
    cvt_bf16_multi<<<dim3((c3 + 255) / 256), dim3(256), 0, stream>>>(
        enc, enc16, c0, dec, dec16, c1, W1, w1_16, c2, W2, w2_16, c3);

    // Both GEMMs in one launch: WE = enc16*W1^T (32 row-blocks) and
    // WD = dec16*W2^T (2 row-blocks); grid (34, 6).
    gemm2_bf16_nt<<<dim3((Bn * Ln) / 128 + (Bn * Tn) / 128, Hn / 128),
                    dim3(256), 0, stream>>>(
        enc16, w1_16, WE16, Bn * Ln,
        dec16, w2_16, WD16, Hn, Hn);

    scores_kernel<<<dim3(2048), dim3(256), 0, stream>>>(WE16, WD16, v, sc);
    softmax_kernel<<<dim3(Bn * Tn), dim3(512), 0, stream>>>(sc, starts, lens, out);
}

// Round 5
// 129.248 us; speedup vs baseline: 1.7975x; 1.0086x over previous
//
#include <hip/hip_runtime.h>
#include <math.h>

// Problem constants (B, T, L, H) = (8, 32, 512, 768)
constexpr int Bn = 8, Tn = 32, Ln = 512, Hn = 768;

typedef __attribute__((ext_vector_type(8))) short bf16x8;   // 8 bf16 = 4 VGPRs
typedef __attribute__((ext_vector_type(4))) float f32x4;

__device__ __forceinline__ short f2bf(float x) {
    unsigned u = __float_as_uint(x);
    u += 0x7FFFu + ((u >> 16) & 1u);
    return (short)(u >> 16);
}
__device__ __forceinline__ float bf2f(unsigned short s) {
    return __uint_as_float(((unsigned)s) << 16);
}

// selu constants
constexpr float kScale = 1.0507009873554804934193349852946f;
constexpr float kAS    = 1.7580993408473768f;   // scale * alpha

__device__ __forceinline__ float selu(float x) {
    return x > 0.f ? kScale * x : fmaf(kAS, __expf(x), -kAS);
}

// ---------------------------------------------------------------------------
// fp32 -> bf16 (RNE) for 4 tensors in one launch; each thread does one float4.
// ---------------------------------------------------------------------------
__global__ __launch_bounds__(256) void cvt_bf16_multi(
    const float* __restrict__ s0, short* __restrict__ d0, int c0,   // cumulative float4 counts
    const float* __restrict__ s1, short* __restrict__ d1, int c1,
    const float* __restrict__ s2, short* __restrict__ d2, int c2,
    const float* __restrict__ s3, short* __restrict__ d3, int c3)
{
    const int i = blockIdx.x * 256 + threadIdx.x;
    if (i >= c3) return;
    const float* s; short* d; int off;
    if (i < c0)      { s = s0; d = d0; off = i; }
    else if (i < c1) { s = s1; d = d1; off = i - c0; }
    else if (i < c2) { s = s2; d = d2; off = i - c1; }
    else             { s = s3; d = d3; off = i - c2; }
    const float4 f = ((const float4*)s)[off];
    short4 r;
    r.x = f2bf(f.x); r.y = f2bf(f.y); r.z = f2bf(f.z); r.w = f2bf(f.w);
    ((short4*)d)[off] = r;
}

// ---------------------------------------------------------------------------
// Merged bf16 NT MFMA GEMM for both WE and WD in ONE launch.
// C[M,N] = A[M,K] * B[N,K]^T, bf16 out.  BM=BN=128, BK=32, 256 threads =
// 4 waves in 2x2; each wave computes 64x64 = 4x4 MFMA 16x16x32 tiles.
// Staging via global_load_lds width=16.
// ---------------------------------------------------------------------------
__global__ __launch_bounds__(256) void gemm2_bf16_nt(
    const short* __restrict__ A1, const short* __restrict__ B1,
    unsigned short* __restrict__ C1, int M1,
    const short* __restrict__ A2, const short* __restrict__ B2,
    unsigned short* __restrict__ C2,
    int N, int K)
{
    constexpr int BM = 128, BN = 128, BK = 32;
    __shared__ __align__(16) short As[BM * BK];
    __shared__ __align__(16) short Bs[BN * BK];

    const int nblk1 = M1 / BM;
    const int bx = blockIdx.x;
    const short* A; const short* Bm; unsigned short* C; int bm;
    if (bx < nblk1) { A = A1; Bm = B1; C = C1; bm = bx * BM; }
    else            { A = A2; Bm = B2; C = C2; bm = (bx - nblk1) * BM; }
    const int bn = blockIdx.y * BN;

    const int tid  = threadIdx.x;
    const int lane = tid & 63;
    const int wv   = tid >> 6;          // 0..3
    const int quad = lane >> 4;         // 0..3
    const int l16  = lane & 15;
    const int wm   = (wv & 1) * 64;
    const int wn   = (wv >> 1) * 64;

    const int sr = lane >> 2;           // 0..15 row within 16-row chunk
    const int kq = (lane & 3) << 3;     // k elem offset: 0,8,16,24

    f32x4 acc[4][4] = {};

    for (int k0 = 0; k0 < K; k0 += BK) {
        const int ra = wv * 16 + sr;    // 0..63
        __builtin_amdgcn_global_load_lds(
            (const __attribute__((address_space(1))) unsigned int*)(A + (size_t)(bm + ra) * K + k0 + kq),
            (__attribute__((address_space(3))) unsigned int*)(As + ra * BK + kq), 16, 0, 0);
        __builtin_amdgcn_global_load_lds(
            (const __attribute__((address_space(1))) unsigned int*)(A + (size_t)(bm + 64 + ra) * K + k0 + kq),
            (__attribute__((address_space(3))) unsigned int*)(As + (64 + ra) * BK + kq), 16, 0, 0);
        __builtin_amdgcn_global_load_lds(
            (const __attribute__((address_space(1))) unsigned int*)(Bm + (size_t)(bn + ra) * K + k0 + kq),
            (__attribute__((address_space(3))) unsigned int*)(Bs + ra * BK + kq), 16, 0, 0);
        __builtin_amdgcn_global_load_lds(
            (const __attribute__((address_space(1))) unsigned int*)(Bm + (size_t)(bn + 64 + ra) * K + k0 + kq),
            (__attribute__((address_space(3))) unsigned int*)(Bs + (64 + ra) * BK + kq), 16, 0, 0);
        __syncthreads();

        bf16x8 af[4], bfr[4];
#pragma unroll
        for (int i = 0; i < 4; ++i)
            af[i] = *(const bf16x8*)&As[(wm + i * 16 + l16) * BK + quad * 8];
#pragma unroll
        for (int j = 0; j < 4; ++j)
            bfr[j] = *(const bf16x8*)&Bs[(wn + j * 16 + l16) * BK + quad * 8];
#pragma unroll
        for (int i = 0; i < 4; ++i)
#pragma unroll
            for (int j = 0; j < 4; ++j)
                acc[i][j] = __builtin_amdgcn_mfma_f32_16x16x32_bf16(af[i], bfr[j], acc[i][j], 0, 0, 0);
        __syncthreads();
    }

    // Epilogue: D mapping col = lane&15, row = quad*4 + rr ; store bf16
#pragma unroll
    for (int i = 0; i < 4; ++i)
#pragma unroll
        for (int j = 0; j < 4; ++j)
#pragma unroll
            for (int rr = 0; rr < 4; ++rr) {
                const int row = bm + wm + i * 16 + quad * 4 + rr;
                const int col = bn + wn + j * 16 + l16;
                C[(size_t)row * N + col] = (unsigned short)f2bf(acc[i][j][rr]);
            }
}

// ---------------------------------------------------------------------------
// Fused scores + masked log-softmax.  One block per (b,t): 512 threads =
// 8 waves.  Scores: groups of 4 l-rows, INTERLEAVED across waves
// (g = wv + 8k) so the masked-region skip stays load-balanced; 4
// independent fma/shuffle chains per group (ILP).  Fully-masked groups are
// skipped — their sc[] entries are never read unmasked downstream.
// Then an in-LDS masked log-softmax over L=512.
// b = bid&7 keeps WE[b] (786 KB bf16) hot in one XCD's L2.
// ---------------------------------------------------------------------------
__global__ __launch_bounds__(512) void scores_softmax_fused(
    const unsigned short* __restrict__ WE,  // [B*L, H] bf16
    const unsigned short* __restrict__ WD,  // [B*T, H] bf16
    const float* __restrict__ v,            // [H]
    const int* __restrict__ starts,         // [B*T]
    const int* __restrict__ lens,           // [B]
    float* __restrict__ out)                // [B*T, L]
{
    const int bid = blockIdx.x;
    const int b = bid & 7;
    const int t = bid >> 3;
    const int bt = b * Tn + t;
    const int tid = threadIdx.x;
    const int lane = tid & 63;
    const int wv = tid >> 6;            // 0..7

    __shared__ float sc[Ln];
    __shared__ float red[16];

    const int start = starts[bt];
    const int len = lens[b];

    // Per-lane fragments of WD row and v: h = 4*lane + 256*j
    float wdr[12], vr[12];
#pragma unroll
    for (int j = 0; j < 3; ++j) {
        const int h = (lane << 2) + (j << 8);
        const ushort4 wdu = *(const ushort4*)(WD + (size_t)bt * Hn + h);
        const float4 vv = *(const float4*)(v + h);
        wdr[j * 4 + 0] = bf2f(wdu.x); wdr[j * 4 + 1] = bf2f(wdu.y);
        wdr[j * 4 + 2] = bf2f(wdu.z); wdr[j * 4 + 3] = bf2f(wdu.w);
        vr[j * 4 + 0] = vv.x; vr[j * 4 + 1] = vv.y;
        vr[j * 4 + 2] = vv.z; vr[j * 4 + 3] = vv.w;
    }

    const unsigned short* WEb = WE + (size_t)b * Ln * Hn;

    for (int k = 0; k < 16; ++k) {
        const int g = wv + (k << 3);    // interleaved group id, 0..127
        const int lg = g << 2;          // first l of this 4-row group
        if (lg + 3 < start || lg >= len) continue;   // fully masked -> skip

        // issue all 12 loads up front (independent)
        ushort4 weu[4][3];
#pragma unroll
        for (int rr = 0; rr < 4; ++rr) {
            const unsigned short* row = WEb + (size_t)(lg + rr) * Hn;
#pragma unroll
            for (int j = 0; j < 3; ++j)
                weu[rr][j] = *(const ushort4*)(row + (lane << 2) + (j << 8));
        }
        float s[4] = {0.f, 0.f, 0.f, 0.f};
#pragma unroll
        for (int j = 0; j < 3; ++j) {
#pragma unroll
            for (int rr = 0; rr < 4; ++rr) {   // 4 independent chains
                float x;
                x = bf2f(weu[rr][j].x) + wdr[j * 4 + 0]; s[rr] = fmaf(selu(x), vr[j * 4 + 0], s[rr]);
                x = bf2f(weu[rr][j].y) + wdr[j * 4 + 1]; s[rr] = fmaf(selu(x), vr[j * 4 + 1], s[rr]);
                x = bf2f(weu[rr][j].z) + wdr[j * 4 + 2]; s[rr] = fmaf(selu(x), vr[j * 4 + 2], s[rr]);
                x = bf2f(weu[rr][j].w) + wdr[j * 4 + 3]; s[rr] = fmaf(selu(x), vr[j * 4 + 3], s[rr]);
            }
        }
        // 4 interleaved shuffle-reduce trees
#pragma unroll
        for (int off = 32; off > 0; off >>= 1) {
#pragma unroll
            for (int rr = 0; rr < 4; ++rr)
                s[rr] += __shfl_xor(s[rr], off, 64);
        }
        if (lane == 0) {
#pragma unroll
            for (int rr = 0; rr < 4; ++rr)
                sc[lg + rr] = selu(s[rr]);
        }
    }
    __syncthreads();

    // ---- masked log-softmax over L (one thread per l) ----
    const int l = tid;                  // blockDim.x == Ln == 512
    const bool msk = (l >= start) && (l < len);
    const float val = msk ? sc[l] : -1e30f;   // masked entries may be uninit LDS

    float mx = val;
#pragma unroll
    for (int off = 32; off > 0; off >>= 1)
        mx = fmaxf(mx, __shfl_xor(mx, off, 64));
    if (lane == 0) red[wv] = mx;
    __syncthreads();
    mx = red[0];
#pragma unroll
    for (int i = 1; i < 8; ++i) mx = fmaxf(mx, red[i]);

    float sm = msk ? __expf(val - mx) : 0.f;
#pragma unroll
    for (int off = 32; off > 0; off >>= 1)
        sm += __shfl_xor(sm, off, 64);
    if (lane == 0) red[8 + wv] = sm;
    __syncthreads();
    float tot = red[8];
#pragma unroll
    for (int i = 1; i < 8; ++i) tot += red[8 + i];

    const float logZ = mx + __logf(tot);
    out[(size_t)bt * Ln + l] = msk ? (val - logZ) : 0.f;
}

// ---------------------------------------------------------------------------
extern "C" void kernel_launch(void* const* d_in, const int* in_sizes, int n_in,
                              void* d_out, int out_size, void* d_ws, size_t ws_size,
                              hipStream_t stream) {
    const float* enc    = (const float*)d_in[0];  // [B, L, H]
    const float* dec    = (const float*)d_in[1];  // [B, T, H]
    const float* W1     = (const float*)d_in[2];  // [H, H]
    const float* W2     = (const float*)d_in[3];  // [H, H]
    const float* v      = (const float*)d_in[4];  // [H]
    const int*   starts = (const int*)d_in[5];    // [B, T]
    const int*   lens   = (const int*)d_in[6];    // [B]
    float* out = (float*)d_out;

    constexpr int n_enc = Bn * Ln * Hn;   // 3,145,728
    constexpr int n_dec = Bn * Tn * Hn;   //   196,608
    constexpr int n_w   = Hn * Hn;        //   589,824

    const size_t need = (size_t)(n_enc + n_dec + 2 * n_w) * 2   // bf16 inputs
                      + (size_t)(n_enc + n_dec) * 2;            // WE16 + WD16
    if (ws_size < need) return;  // visible failure

    short* enc16 = (short*)d_ws;
    short* dec16 = enc16 + n_enc;
    short* w1_16 = dec16 + n_dec;
    short* w2_16 = w1_16 + n_w;
    unsigned short* WE16 = (unsigned short*)(w2_16 + n_w);
    unsigned short* WD16 = WE16 + n_enc;

    constexpr int c0 = n_enc / 4;
    constexpr int c1 = c0 + n_dec / 4;
    constexpr int c2 = c1 + n_w / 4;
    constexpr int c3 = c2 + n_w / 4;
    cvt_bf16_multi<<<dim3((c3 + 255) / 256), dim3(256), 0, stream>>>(
        enc, enc16, c0, dec, dec16, c1, W1, w1_16, c2, W2, w2_16, c3);

    // Both GEMMs in one launch: WE = enc16*W1^T (32 row-blocks) and
    // WD = dec16*W2^T (2 row-blocks); grid (34, 6).
    gemm2_bf16_nt<<<dim3((Bn * Ln) / 128 + (Bn * Tn) / 128, Hn / 128),
                    dim3(256), 0, stream>>>(
        enc16, w1_16, WE16, Bn * Ln,
        dec16, w2_16, WD16, Hn, Hn);

    scores_softmax_fused<<<dim3(Bn * Tn), dim3(512), 0, stream>>>(
        WE16, WD16, v, starts, lens, out);
}

// Round 6
// 125.495 us; speedup vs baseline: 1.8513x; 1.0299x over previous
//
#include <hip/hip_runtime.h>
#include <math.h>

// Problem constants (B, T, L, H) = (8, 32, 512, 768)
constexpr int Bn = 8, Tn = 32, Ln = 512, Hn = 768;

typedef __attribute__((ext_vector_type(8))) short bf16x8;   // 8 bf16 = 4 VGPRs
typedef __attribute__((ext_vector_type(4))) float f32x4;

__device__ __forceinline__ short f2bf(float x) {
    unsigned u = __float_as_uint(x);
    u += 0x7FFFu + ((u >> 16) & 1u);
    return (short)(u >> 16);
}
__device__ __forceinline__ float bf2f(unsigned short s) {
    return __uint_as_float(((unsigned)s) << 16);
}

// selu constants
constexpr float kScale = 1.0507009873554804934193349852946f;
constexpr float kAS    = 1.7580993408473768f;   // scale * alpha

__device__ __forceinline__ float selu(float x) {
    return x > 0.f ? kScale * x : fmaf(kAS, __expf(x), -kAS);
}

// ---------------------------------------------------------------------------
// fp32 -> bf16 (RNE) for 4 tensors in one launch; each thread does one float4.
// ---------------------------------------------------------------------------
__global__ __launch_bounds__(256) void cvt_bf16_multi(
    const float* __restrict__ s0, short* __restrict__ d0, int c0,   // cumulative float4 counts
    const float* __restrict__ s1, short* __restrict__ d1, int c1,
    const float* __restrict__ s2, short* __restrict__ d2, int c2,
    const float* __restrict__ s3, short* __restrict__ d3, int c3)
{
    const int i = blockIdx.x * 256 + threadIdx.x;
    if (i >= c3) return;
    const float* s; short* d; int off;
    if (i < c0)      { s = s0; d = d0; off = i; }
    else if (i < c1) { s = s1; d = d1; off = i - c0; }
    else if (i < c2) { s = s2; d = d2; off = i - c1; }
    else             { s = s3; d = d3; off = i - c2; }
    const float4 f = ((const float4*)s)[off];
    short4 r;
    r.x = f2bf(f.x); r.y = f2bf(f.y); r.z = f2bf(f.z); r.w = f2bf(f.w);
    ((short4*)d)[off] = r;
}

// ---------------------------------------------------------------------------
// Merged bf16 NT MFMA GEMM for both WE and WD in ONE launch.
// C[M,N] = A[M,K] * B[N,K]^T, bf16 out.  BM=BN=128, BK=32, 256 threads =
// 4 waves in 2x2; each wave computes 64x64 = 4x4 MFMA 16x16x32 tiles.
// DOUBLE-BUFFERED LDS: with 204 blocks on 256 CUs (1 wave/SIMD) there is no
// inter-block latency hiding, so tile k+1 is prefetched via global_load_lds
// into the alternate buffer while MFMAs consume the current one; a single
// barrier per iteration drains both.
// ---------------------------------------------------------------------------
__global__ __launch_bounds__(256) void gemm2_bf16_nt(
    const short* __restrict__ A1, const short* __restrict__ B1,
    unsigned short* __restrict__ C1, int M1,
    const short* __restrict__ A2, const short* __restrict__ B2,
    unsigned short* __restrict__ C2,
    int N, int K)
{
    constexpr int BM = 128, BN = 128, BK = 32;
    __shared__ __align__(16) short As[2][BM * BK];
    __shared__ __align__(16) short Bs[2][BN * BK];

    const int nblk1 = M1 / BM;
    const int bx = blockIdx.x;
    const short* A; const short* Bm; unsigned short* C; int bm;
    if (bx < nblk1) { A = A1; Bm = B1; C = C1; bm = bx * BM; }
    else            { A = A2; Bm = B2; C = C2; bm = (bx - nblk1) * BM; }
    const int bn = blockIdx.y * BN;

    const int tid  = threadIdx.x;
    const int lane = tid & 63;
    const int wv   = tid >> 6;          // 0..3
    const int quad = lane >> 4;         // 0..3
    const int l16  = lane & 15;
    const int wm   = (wv & 1) * 64;
    const int wn   = (wv >> 1) * 64;

    const int sr = lane >> 2;           // 0..15 row within 16-row chunk
    const int kq = (lane & 3) << 3;     // k elem offset: 0,8,16,24
    const int ra = wv * 16 + sr;        // 0..63

    f32x4 acc[4][4] = {};

    // stage tile at k0 into buffer `buf`
    auto stage = [&](int buf, int k0) {
        __builtin_amdgcn_global_load_lds(
            (const __attribute__((address_space(1))) unsigned int*)(A + (size_t)(bm + ra) * K + k0 + kq),
            (__attribute__((address_space(3))) unsigned int*)(&As[buf][ra * BK + kq]), 16, 0, 0);
        __builtin_amdgcn_global_load_lds(
            (const __attribute__((address_space(1))) unsigned int*)(A + (size_t)(bm + 64 + ra) * K + k0 + kq),
            (__attribute__((address_space(3))) unsigned int*)(&As[buf][(64 + ra) * BK + kq]), 16, 0, 0);
        __builtin_amdgcn_global_load_lds(
            (const __attribute__((address_space(1))) unsigned int*)(Bm + (size_t)(bn + ra) * K + k0 + kq),
            (__attribute__((address_space(3))) unsigned int*)(&Bs[buf][ra * BK + kq]), 16, 0, 0);
        __builtin_amdgcn_global_load_lds(
            (const __attribute__((address_space(1))) unsigned int*)(Bm + (size_t)(bn + 64 + ra) * K + k0 + kq),
            (__attribute__((address_space(3))) unsigned int*)(&Bs[buf][(64 + ra) * BK + kq]), 16, 0, 0);
    };

    stage(0, 0);
    __syncthreads();                    // buf0 ready

    for (int k0 = 0; k0 < K; k0 += BK) {
        const int cur = (k0 / BK) & 1;
        const int nxt = cur ^ 1;
        if (k0 + BK < K) stage(nxt, k0 + BK);   // prefetch overlaps MFMA below

        bf16x8 af[4], bfr[4];
#pragma unroll
        for (int i = 0; i < 4; ++i)
            af[i] = *(const bf16x8*)&As[cur][(wm + i * 16 + l16) * BK + quad * 8];
#pragma unroll
        for (int j = 0; j < 4; ++j)
            bfr[j] = *(const bf16x8*)&Bs[cur][(wn + j * 16 + l16) * BK + quad * 8];
#pragma unroll
        for (int i = 0; i < 4; ++i)
#pragma unroll
            for (int j = 0; j < 4; ++j)
                acc[i][j] = __builtin_amdgcn_mfma_f32_16x16x32_bf16(af[i], bfr[j], acc[i][j], 0, 0, 0);
        __syncthreads();                // drains prefetch + protects cur reuse
    }

    // Epilogue: D mapping col = lane&15, row = quad*4 + rr ; store bf16
#pragma unroll
    for (int i = 0; i < 4; ++i)
#pragma unroll
        for (int j = 0; j < 4; ++j)
#pragma unroll
            for (int rr = 0; rr < 4; ++rr) {
                const int row = bm + wm + i * 16 + quad * 4 + rr;
                const int col = bn + wn + j * 16 + l16;
                C[(size_t)row * N + col] = (unsigned short)f2bf(acc[i][j][rr]);
            }
}

// ---------------------------------------------------------------------------
// Fused scores + masked log-softmax.  One block per (b,t): 1024 threads =
// 16 waves (4 waves/SIMD at 1 block/CU).  Scores: groups of 4 l-rows,
// interleaved across waves (g = wv + 16k) for load-balanced mask skipping;
// 4 independent fma/shuffle chains per group (ILP).  Fully-masked groups
// skipped.  Softmax phase: first 512 threads, one per l.
// b = bid&7 keeps WE[b] (786 KB bf16) hot in one XCD's L2.
// ---------------------------------------------------------------------------
__global__ __launch_bounds__(1024) void scores_softmax_fused(
    const unsigned short* __restrict__ WE,  // [B*L, H] bf16
    const unsigned short* __restrict__ WD,  // [B*T, H] bf16
    const float* __restrict__ v,            // [H]
    const int* __restrict__ starts,         // [B*T]
    const int* __restrict__ lens,           // [B]
    float* __restrict__ out)                // [B*T, L]
{
    const int bid = blockIdx.x;
    const int b = bid & 7;
    const int t = bid >> 3;
    const int bt = b * Tn + t;
    const int tid = threadIdx.x;
    const int lane = tid & 63;
    const int wv = tid >> 6;            // 0..15

    __shared__ float sc[Ln];
    __shared__ float red[16];

    const int start = starts[bt];
    const int len = lens[b];

    // Per-lane fragments of WD row and v: h = 4*lane + 256*j
    float wdr[12], vr[12];
#pragma unroll
    for (int j = 0; j < 3; ++j) {
        const int h = (lane << 2) + (j << 8);
        const ushort4 wdu = *(const ushort4*)(WD + (size_t)bt * Hn + h);
        const float4 vv = *(const float4*)(v + h);
        wdr[j * 4 + 0] = bf2f(wdu.x); wdr[j * 4 + 1] = bf2f(wdu.y);
        wdr[j * 4 + 2] = bf2f(wdu.z); wdr[j * 4 + 3] = bf2f(wdu.w);
        vr[j * 4 + 0] = vv.x; vr[j * 4 + 1] = vv.y;
        vr[j * 4 + 2] = vv.z; vr[j * 4 + 3] = vv.w;
    }

    const unsigned short* WEb = WE + (size_t)b * Ln * Hn;

    for (int k = 0; k < 8; ++k) {
        const int g = wv + (k << 4);    // interleaved group id, 0..127
        const int lg = g << 2;          // first l of this 4-row group
        if (lg + 3 < start || lg >= len) continue;   // fully masked -> skip

        // issue all 12 loads up front (independent)
        ushort4 weu[4][3];
#pragma unroll
        for (int rr = 0; rr < 4; ++rr) {
            const unsigned short* row = WEb + (size_t)(lg + rr) * Hn;
#pragma unroll
            for (int j = 0; j < 3; ++j)
                weu[rr][j] = *(const ushort4*)(row + (lane << 2) + (j << 8));
        }
        float s[4] = {0.f, 0.f, 0.f, 0.f};
#pragma unroll
        for (int j = 0; j < 3; ++j) {
#pragma unroll
            for (int rr = 0; rr < 4; ++rr) {   // 4 independent chains
                float x;
                x = bf2f(weu[rr][j].x) + wdr[j * 4 + 0]; s[rr] = fmaf(selu(x), vr[j * 4 + 0], s[rr]);
                x = bf2f(weu[rr][j].y) + wdr[j * 4 + 1]; s[rr] = fmaf(selu(x), vr[j * 4 + 1], s[rr]);
                x = bf2f(weu[rr][j].z) + wdr[j * 4 + 2]; s[rr] = fmaf(selu(x), vr[j * 4 + 2], s[rr]);
                x = bf2f(weu[rr][j].w) + wdr[j * 4 + 3]; s[rr] = fmaf(selu(x), vr[j * 4 + 3], s[rr]);
            }
        }
        // 4 interleaved shuffle-reduce trees
#pragma unroll
        for (int off = 32; off > 0; off >>= 1) {
#pragma unroll
            for (int rr = 0; rr < 4; ++rr)
                s[rr] += __shfl_xor(s[rr], off, 64);
        }
        if (lane == 0) {
#pragma unroll
            for (int rr = 0; rr < 4; ++rr)
                sc[lg + rr] = selu(s[rr]);
        }
    }
    __syncthreads();

    // ---- masked log-softmax over L (threads 0..511, one per l) ----
    const int l = tid;
    const bool active = (l < Ln);
    const bool msk = active && (l >= start) && (l < len);
    const float val = msk ? sc[l] : -1e30f;

    float mx = val;
#pragma unroll
    for (int off = 32; off > 0; off >>= 1)
        mx = fmaxf(mx, __shfl_xor(mx, off, 64));
    if (lane == 0 && wv < 8) red[wv] = mx;
    __syncthreads();
    mx = red[0];
#pragma unroll
    for (int i = 1; i < 8; ++i) mx = fmaxf(mx, red[i]);

    float sm = msk ? __expf(val - mx) : 0.f;
#pragma unroll
    for (int off = 32; off > 0; off >>= 1)
        sm += __shfl_xor(sm, off, 64);
    if (lane == 0 && wv < 8) red[8 + wv] = sm;
    __syncthreads();
    float tot = red[8];
#pragma unroll
    for (int i = 1; i < 8; ++i) tot += red[8 + i];

    if (active) {
        const float logZ = mx + __logf(tot);
        out[(size_t)bt * Ln + l] = msk ? (val - logZ) : 0.f;
    }
}

// ---------------------------------------------------------------------------
extern "C" void kernel_launch(void* const* d_in, const int* in_sizes, int n_in,
                              void* d_out, int out_size, void* d_ws, size_t ws_size,
                              hipStream_t stream) {
    const float* enc    = (const float*)d_in[0];  // [B, L, H]
    const float* dec    = (const float*)d_in[1];  // [B, T, H]
    const float* W1     = (const float*)d_in[2];  // [H, H]
    const float* W2     = (const float*)d_in[3];  // [H, H]
    const float* v      = (const float*)d_in[4];  // [H]
    const int*   starts = (const int*)d_in[5];    // [B, T]
    const int*   lens   = (const int*)d_in[6];    // [B]
    float* out = (float*)d_out;

    constexpr int n_enc = Bn * Ln * Hn;   // 3,145,728
    constexpr int n_dec = Bn * Tn * Hn;   //   196,608
    constexpr int n_w   = Hn * Hn;        //   589,824

    const size_t need = (size_t)(n_enc + n_dec + 2 * n_w) * 2   // bf16 inputs
                      + (size_t)(n_enc + n_dec) * 2;            // WE16 + WD16
    if (ws_size < need) return;  // visible failure

    short* enc16 = (short*)d_ws;
    short* dec16 = enc16 + n_enc;
    short* w1_16 = dec16 + n_dec;
    short* w2_16 = w1_16 + n_w;
    unsigned short* WE16 = (unsigned short*)(w2_16 + n_w);
    unsigned short* WD16 = WE16 + n_enc;

    constexpr int c0 = n_enc / 4;
    constexpr int c1 = c0 + n_dec / 4;
    constexpr int c2 = c1 + n_w / 4;
    constexpr int c3 = c2 + n_w / 4;
    cvt_bf16_multi<<<dim3((c3 + 255) / 256), dim3(256), 0, stream>>>(
        enc, enc16, c0, dec, dec16, c1, W1, w1_16, c2, W2, w2_16, c3);

    // Both GEMMs in one launch: WE = enc16*W1^T (32 row-blocks) and
    // WD = dec16*W2^T (2 row-blocks); grid (34, 6).
    gemm2_bf16_nt<<<dim3((Bn * Ln) / 128 + (Bn * Tn) / 128, Hn / 128),
                    dim3(256), 0, stream>>>(
        enc16, w1_16, WE16, Bn * Ln,
        dec16, w2_16, WD16, Hn, Hn);

    scores_softmax_fused<<<dim3(Bn * Tn), dim3(1024), 0, stream>>>(
        WE16, WD16, v, starts, lens, out);
}

// Round 7
// 121.974 us; speedup vs baseline: 1.9047x; 1.0289x over previous
//
#include <hip/hip_runtime.h>
#include <math.h>

// Problem constants (B, T, L, H) = (8, 32, 512, 768)
constexpr int Bn = 8, Tn = 32, Ln = 512, Hn = 768;

typedef __attribute__((ext_vector_type(8))) short bf16x8;   // 8 bf16 = 4 VGPRs
typedef __attribute__((ext_vector_type(4))) float f32x4;

__device__ __forceinline__ short f2bf(float x) {
    unsigned u = __float_as_uint(x);
    u += 0x7FFFu + ((u >> 16) & 1u);
    return (short)(u >> 16);
}
__device__ __forceinline__ float bf2f(unsigned short s) {
    return __uint_as_float(((unsigned)s) << 16);
}

// selu constants
constexpr float kScale = 1.0507009873554804934193349852946f;
constexpr float kAS    = 1.7580993408473768f;   // scale * alpha

__device__ __forceinline__ float selu(float x) {
    return x > 0.f ? kScale * x : fmaf(kAS, __expf(x), -kAS);
}

__device__ __forceinline__ bf16x8 pack8(float4 a, float4 b) {
    bf16x8 r;
    r[0] = f2bf(a.x); r[1] = f2bf(a.y); r[2] = f2bf(a.z); r[3] = f2bf(a.w);
    r[4] = f2bf(b.x); r[5] = f2bf(b.y); r[6] = f2bf(b.z); r[7] = f2bf(b.w);
    return r;
}

// ---------------------------------------------------------------------------
// Merged NT MFMA GEMM with FUSED fp32->bf16 conversion, both problems in one
// launch.  C[M,N] = bf16(A[M,K]) * bf16(B[N,K])^T, bf16 out.
// BM=BN=128, BK=32, 256 threads = 4 waves; each wave computes 64x64 = 4x4
// MFMA 16x16x32 tiles.  Staging: fp32 global -> registers (prefetched one
// K-step ahead, overlapping the MFMA phase) -> RNE-convert -> ds_write_b128
// at a sequential layout (unit = tid + 256p -> 16 contiguous bytes): zero
// bank conflicts, and the LDS image is IDENTICAL to R6's layout so the
// MFMA fragment reads are unchanged.
// ---------------------------------------------------------------------------
__global__ __launch_bounds__(256) void gemm2_f32_nt(
    const float* __restrict__ A1, const float* __restrict__ B1,
    unsigned short* __restrict__ C1, int M1,
    const float* __restrict__ A2, const float* __restrict__ B2,
    unsigned short* __restrict__ C2,
    int N, int K)
{
    constexpr int BM = 128, BN = 128, BK = 32;
    __shared__ __align__(16) short As[BM * BK];
    __shared__ __align__(16) short Bs[BN * BK];

    const int nblk1 = M1 / BM;
    const int bx = blockIdx.x;
    const float* A; const float* Bm; unsigned short* C; int bm;
    if (bx < nblk1) { A = A1; Bm = B1; C = C1; bm = bx * BM; }
    else            { A = A2; Bm = B2; C = C2; bm = (bx - nblk1) * BM; }
    const int bn = blockIdx.y * BN;

    const int tid  = threadIdx.x;
    const int lane = tid & 63;
    const int wv   = tid >> 6;          // 0..3
    const int quad = lane >> 4;         // 0..3
    const int l16  = lane & 15;
    const int wm   = (wv & 1) * 64;
    const int wn   = (wv >> 1) * 64;

    // staging unit p=0,1: unit = tid + 256p -> row = unit>>2, k = (unit&3)*8
    int srow[2], skk[2];
#pragma unroll
    for (int p = 0; p < 2; ++p) {
        const int unit = tid + (p << 8);
        srow[p] = unit >> 2;
        skk[p]  = (unit & 3) << 3;
    }

    f32x4 acc[4][4] = {};

    float4 cra[2][2], crb[2][2], nra[2][2], nrb[2][2];

    // load fp32 staging registers for tile at k0
    auto gload = [&](float4 ra[2][2], float4 rb[2][2], int k0) {
#pragma unroll
        for (int p = 0; p < 2; ++p) {
            const float* pa = A  + (size_t)(bm + srow[p]) * K + k0 + skk[p];
            ra[p][0] = *(const float4*)pa;
            ra[p][1] = *(const float4*)(pa + 4);
            const float* pb = Bm + (size_t)(bn + srow[p]) * K + k0 + skk[p];
            rb[p][0] = *(const float4*)pb;
            rb[p][1] = *(const float4*)(pb + 4);
        }
    };

    gload(cra, crb, 0);

    for (int k0 = 0; k0 < K; k0 += BK) {
        if (k0 + BK < K) gload(nra, nrb, k0 + BK);   // overlaps everything below
        if (k0 > 0) __syncthreads();                  // prev iter's ds_reads done
        // convert + stage (sequential 16B units -> conflict-free)
#pragma unroll
        for (int p = 0; p < 2; ++p) {
            const int off = (tid + (p << 8)) << 3;    // elem offset, unit*8
            *(bf16x8*)&As[off] = pack8(cra[p][0], cra[p][1]);
            *(bf16x8*)&Bs[off] = pack8(crb[p][0], crb[p][1]);
        }
        __syncthreads();

        bf16x8 af[4], bfr[4];
#pragma unroll
        for (int i = 0; i < 4; ++i)
            af[i] = *(const bf16x8*)&As[(wm + i * 16 + l16) * BK + quad * 8];
#pragma unroll
        for (int j = 0; j < 4; ++j)
            bfr[j] = *(const bf16x8*)&Bs[(wn + j * 16 + l16) * BK + quad * 8];
#pragma unroll
        for (int i = 0; i < 4; ++i)
#pragma unroll
            for (int j = 0; j < 4; ++j)
                acc[i][j] = __builtin_amdgcn_mfma_f32_16x16x32_bf16(af[i], bfr[j], acc[i][j], 0, 0, 0);

        // rotate staging registers
#pragma unroll
        for (int p = 0; p < 2; ++p) {
            cra[p][0] = nra[p][0]; cra[p][1] = nra[p][1];
            crb[p][0] = nrb[p][0]; crb[p][1] = nrb[p][1];
        }
    }

    // Epilogue: D mapping col = lane&15, row = quad*4 + rr ; store bf16
#pragma unroll
    for (int i = 0; i < 4; ++i)
#pragma unroll
        for (int j = 0; j < 4; ++j)
#pragma unroll
            for (int rr = 0; rr < 4; ++rr) {
                const int row = bm + wm + i * 16 + quad * 4 + rr;
                const int col = bn + wn + j * 16 + l16;
                C[(size_t)row * N + col] = (unsigned short)f2bf(acc[i][j][rr]);
            }
}

// ---------------------------------------------------------------------------
// Fused scores + masked log-softmax.  One block per (b,t): 1024 threads =
// 16 waves (4 waves/SIMD at 1 block/CU).  Scores: groups of 4 l-rows,
// interleaved across waves (g = wv + 16k) for load-balanced mask skipping;
// 4 independent fma/shuffle chains per group (ILP).  Fully-masked groups
// skipped.  Softmax phase: first 512 threads, one per l.
// b = bid&7 keeps WE[b] (786 KB bf16) hot in one XCD's L2.
// ---------------------------------------------------------------------------
__global__ __launch_bounds__(1024) void scores_softmax_fused(
    const unsigned short* __restrict__ WE,  // [B*L, H] bf16
    const unsigned short* __restrict__ WD,  // [B*T, H] bf16
    const float* __restrict__ v,            // [H]
    const int* __restrict__ starts,         // [B*T]
    const int* __restrict__ lens,           // [B]
    float* __restrict__ out)                // [B*T, L]
{
    const int bid = blockIdx.x;
    const int b = bid & 7;
    const int t = bid >> 3;
    const int bt = b * Tn + t;
    const int tid = threadIdx.x;
    const int lane = tid & 63;
    const int wv = tid >> 6;            // 0..15

    __shared__ float sc[Ln];
    __shared__ float red[16];

    const int start = starts[bt];
    const int len = lens[b];

    // Per-lane fragments of WD row and v: h = 4*lane + 256*j
    float wdr[12], vr[12];
#pragma unroll
    for (int j = 0; j < 3; ++j) {
        const int h = (lane << 2) + (j << 8);
        const ushort4 wdu = *(const ushort4*)(WD + (size_t)bt * Hn + h);
        const float4 vv = *(const float4*)(v + h);
        wdr[j * 4 + 0] = bf2f(wdu.x); wdr[j * 4 + 1] = bf2f(wdu.y);
        wdr[j * 4 + 2] = bf2f(wdu.z); wdr[j * 4 + 3] = bf2f(wdu.w);
        vr[j * 4 + 0] = vv.x; vr[j * 4 + 1] = vv.y;
        vr[j * 4 + 2] = vv.z; vr[j * 4 + 3] = vv.w;
    }

    const unsigned short* WEb = WE + (size_t)b * Ln * Hn;

    for (int k = 0; k < 8; ++k) {
        const int g = wv + (k << 4);    // interleaved group id, 0..127
        const int lg = g << 2;          // first l of this 4-row group
        if (lg + 3 < start || lg >= len) continue;   // fully masked -> skip

        // issue all 12 loads up front (independent)
        ushort4 weu[4][3];
#pragma unroll
        for (int rr = 0; rr < 4; ++rr) {
            const unsigned short* row = WEb + (size_t)(lg + rr) * Hn;
#pragma unroll
            for (int j = 0; j < 3; ++j)
                weu[rr][j] = *(const ushort4*)(row + (lane << 2) + (j << 8));
        }
        float s[4] = {0.f, 0.f, 0.f, 0.f};
#pragma unroll
        for (int j = 0; j < 3; ++j) {
#pragma unroll
            for (int rr = 0; rr < 4; ++rr) {   // 4 independent chains
                float x;
                x = bf2f(weu[rr][j].x) + wdr[j * 4 + 0]; s[rr] = fmaf(selu(x), vr[j * 4 + 0], s[rr]);
                x = bf2f(weu[rr][j].y) + wdr[j * 4 + 1]; s[rr] = fmaf(selu(x), vr[j * 4 + 1], s[rr]);
                x = bf2f(weu[rr][j].z) + wdr[j * 4 + 2]; s[rr] = fmaf(selu(x), vr[j * 4 + 2], s[rr]);
                x = bf2f(weu[rr][j].w) + wdr[j * 4 + 3]; s[rr] = fmaf(selu(x), vr[j * 4 + 3], s[rr]);
            }
        }
        // 4 interleaved shuffle-reduce trees
#pragma unroll
        for (int off = 32; off > 0; off >>= 1) {
#pragma unroll
            for (int rr = 0; rr < 4; ++rr)
                s[rr] += __shfl_xor(s[rr], off, 64);
        }
        if (lane == 0) {
#pragma unroll
            for (int rr = 0; rr < 4; ++rr)
                sc[lg + rr] = selu(s[rr]);
        }
    }
    __syncthreads();

    // ---- masked log-softmax over L (threads 0..511, one per l) ----
    const int l = tid;
    const bool active = (l < Ln);
    const bool msk = active && (l >= start) && (l < len);
    const float val = msk ? sc[l] : -1e30f;

    float mx = val;
#pragma unroll
    for (int off = 32; off > 0; off >>= 1)
        mx = fmaxf(mx, __shfl_xor(mx, off, 64));
    if (lane == 0 && wv < 8) red[wv] = mx;
    __syncthreads();
    mx = red[0];
#pragma unroll
    for (int i = 1; i < 8; ++i) mx = fmaxf(mx, red[i]);

    float sm = msk ? __expf(val - mx) : 0.f;
#pragma unroll
    for (int off = 32; off > 0; off >>= 1)
        sm += __shfl_xor(sm, off, 64);
    if (lane == 0 && wv < 8) red[8 + wv] = sm;
    __syncthreads();
    float tot = red[8];
#pragma unroll
    for (int i = 1; i < 8; ++i) tot += red[8 + i];

    if (active) {
        const float logZ = mx + __logf(tot);
        out[(size_t)bt * Ln + l] = msk ? (val - logZ) : 0.f;
    }
}

// ---------------------------------------------------------------------------
extern "C" void kernel_launch(void* const* d_in, const int* in_sizes, int n_in,
                              void* d_out, int out_size, void* d_ws, size_t ws_size,
                              hipStream_t stream) {
    const float* enc    = (const float*)d_in[0];  // [B, L, H]
    const float* dec    = (const float*)d_in[1];  // [B, T, H]
    const float* W1     = (const float*)d_in[2];  // [H, H]
    const float* W2     = (const float*)d_in[3];  // [H, H]
    const float* v      = (const float*)d_in[4];  // [H]
    const int*   starts = (const int*)d_in[5];    // [B, T]
    const int*   lens   = (const int*)d_in[6];    // [B]
    float* out = (float*)d_out;

    constexpr int n_enc = Bn * Ln * Hn;   // 3,145,728
    constexpr int n_dec = Bn * Tn * Hn;   //   196,608

    const size_t need = (size_t)(n_enc + n_dec) * 2;   // WE16 + WD16
    if (ws_size < need) return;  // visible failure

    unsigned short* WE16 = (unsigned short*)d_ws;
    unsigned short* WD16 = WE16 + n_enc;

    // Both GEMMs (with fused fp32->bf16 input conversion) in one launch:
    // WE = enc*W1^T (32 row-blocks) and WD = dec*W2^T (2 row-blocks).
    gemm2_f32_nt<<<dim3((Bn * Ln) / 128 + (Bn * Tn) / 128, Hn / 128),
                   dim3(256), 0, stream>>>(
        enc, W1, WE16, Bn * Ln,
        dec, W2, WD16, Hn, Hn);

    scores_softmax_fused<<<dim3(Bn * Tn), dim3(1024), 0, stream>>>(
        WE16, WD16, v, starts, lens, out);
}